// Round 1
// baseline (395.040 us; speedup 1.0000x reference)
//
#include <hip/hip_runtime.h>
#include <hip/hip_bf16.h>

// MHA (no softmax!) = 5 GEMMs per head, all in B^T ("bt") form:
//   Q  = gemm_bt(X_h [4096x1024, ld 2048], Wq [1024x1024])      -> bf16
//   K  = gemm_bt(X_h, Wk)                                       -> bf16
//   Vt = gemm_bt(Wv [1024x1024], X_h [4096x1024, ld 2048])      -> bf16 (V^T, 1024x4096)
//   S  = gemm_bt(Q  [4096x1024], K [4096x1024])                 -> bf16 (4096x4096)
//   O  = gemm_bt(S  [4096x4096], Vt [1024x4096]) -> f32 into out[:, h*1024:]
// m97 structure: 128x128 tile, BK=32, 4 waves (2x2 of 64x64 subtiles),
// global_load_lds width=16 staging, mfma_f32_16x16x32_bf16, 2 barriers/K-step.

using bf16 = __hip_bfloat16;
typedef __attribute__((ext_vector_type(8))) __bf16 bf16x8;
typedef __attribute__((ext_vector_type(4))) float f32x4;

#define BM 128
#define BN 128
#define BK 32

__device__ __forceinline__ void gload_lds16(const void* g, void* l) {
    __builtin_amdgcn_global_load_lds(
        (const __attribute__((address_space(1))) void*)g,
        (__attribute__((address_space(3))) void*)l, 16, 0, 0);
}

__device__ __forceinline__ void storeC(bf16* C, size_t idx, float v) {
    C[idx] = __float2bfloat16(v);
}
__device__ __forceinline__ void storeC(float* C, size_t idx, float v) {
    C[idx] = v;
}

// A: M x K row-major (stride lda), B: Nd x K row-major (stride ldb)  [B^T form]
// C: M x Nd (stride ldc).  M, Nd multiples of 128; K multiple of 32.
template<typename OUT_T>
__global__ __launch_bounds__(256, 2)
void gemm_bt(const bf16* __restrict__ A, const bf16* __restrict__ B,
             OUT_T* __restrict__ C,
             int K, int lda, int ldb, int ldc)
{
    __shared__ unsigned short As[BM * BK];   // [128][32] bf16, linear (gload_lds needs it)
    __shared__ unsigned short Bs[BN * BK];

    const int tid  = threadIdx.x;
    const int lane = tid & 63;
    const int wave = tid >> 6;     // 0..3
    const int wm   = wave >> 1;    // 0..1  (row half)
    const int wn   = wave & 1;     // 0..1  (col half)

    const int m0 = blockIdx.y * BM;
    const int n0 = blockIdx.x * BN;

    const int fr = lane & 15;      // fragment row/col index
    const int kg = lane >> 4;      // k-group 0..3 (8 bf16 each)

    // staging: thread t covers LDS bytes [r*4096 + t*16, +16) == element (r*64+t/4)*32 + (t%4)*8
    const int srow = tid >> 2;          // 0..63
    const int scol = (tid & 3) * 8;     // 0,8,16,24

    f32x4 acc[4][4];
    #pragma unroll
    for (int i = 0; i < 4; ++i)
        #pragma unroll
        for (int j = 0; j < 4; ++j)
            acc[i][j] = {0.f, 0.f, 0.f, 0.f};

    for (int kt = 0; kt < K; kt += BK) {
        #pragma unroll
        for (int r = 0; r < 2; ++r) {
            const bf16* gA = A + (size_t)(m0 + r * 64 + srow) * lda + (kt + scol);
            gload_lds16(gA, &As[(r * 64 + srow) * BK + scol]);
            const bf16* gB = B + (size_t)(n0 + r * 64 + srow) * ldb + (kt + scol);
            gload_lds16(gB, &Bs[(r * 64 + srow) * BK + scol]);
        }
        __syncthreads();   // compiler emits vmcnt(0) drain before barrier

        bf16x8 afrag[4], bfrag[4];
        #pragma unroll
        for (int mi = 0; mi < 4; ++mi)
            afrag[mi] = *(const bf16x8*)&As[(wm * 64 + mi * 16 + fr) * BK + kg * 8];
        #pragma unroll
        for (int ni = 0; ni < 4; ++ni)
            bfrag[ni] = *(const bf16x8*)&Bs[(wn * 64 + ni * 16 + fr) * BK + kg * 8];

        #pragma unroll
        for (int mi = 0; mi < 4; ++mi)
            #pragma unroll
            for (int ni = 0; ni < 4; ++ni)
                acc[mi][ni] = __builtin_amdgcn_mfma_f32_16x16x32_bf16(
                    afrag[mi], bfrag[ni], acc[mi][ni], 0, 0, 0);
        __syncthreads();
    }

    // epilogue: C/D layout col = lane&15, row = (lane>>4)*4 + j  [m89-verified]
    #pragma unroll
    for (int mi = 0; mi < 4; ++mi) {
        #pragma unroll
        for (int ni = 0; ni < 4; ++ni) {
            const int col = n0 + wn * 64 + ni * 16 + fr;
            #pragma unroll
            for (int j = 0; j < 4; ++j) {
                const int row = m0 + wm * 64 + mi * 16 + kg * 4 + j;
                storeC(C, (size_t)row * ldc + col, acc[mi][ni][j]);
            }
        }
    }
}

__global__ void cast_f32_bf16(const float* __restrict__ src, bf16* __restrict__ dst, int n4)
{
    int i = blockIdx.x * blockDim.x + threadIdx.x;
    const int stride = gridDim.x * blockDim.x;
    for (; i < n4; i += stride) {
        float4 v = reinterpret_cast<const float4*>(src)[i];
        ushort4 o;
        bf16 h;
        h = __float2bfloat16(v.x); o.x = *reinterpret_cast<unsigned short*>(&h);
        h = __float2bfloat16(v.y); o.y = *reinterpret_cast<unsigned short*>(&h);
        h = __float2bfloat16(v.z); o.z = *reinterpret_cast<unsigned short*>(&h);
        h = __float2bfloat16(v.w); o.w = *reinterpret_cast<unsigned short*>(&h);
        reinterpret_cast<ushort4*>(dst)[i] = o;
    }
}

extern "C" void kernel_launch(void* const* d_in, const int* in_sizes, int n_in,
                              void* d_out, int out_size, void* d_ws, size_t ws_size,
                              hipStream_t stream)
{
    const int N = 4096, D = 2048, DH = 1024;

    const float* x  = (const float*)d_in[0];
    const float* Wq[2] = {(const float*)d_in[1], (const float*)d_in[2]};
    const float* Wk[2] = {(const float*)d_in[3], (const float*)d_in[4]};
    const float* Wv[2] = {(const float*)d_in[5], (const float*)d_in[6]};
    float* out = (float*)d_out;

    // workspace layout (bf16), ~84 MB total
    bf16* xb = (bf16*)d_ws;
    bf16* p  = xb + (size_t)N * D;
    bf16* wqb[2]; bf16* wkb[2]; bf16* wvb[2];
    wqb[0] = p; p += (size_t)DH * DH;
    wqb[1] = p; p += (size_t)DH * DH;
    wkb[0] = p; p += (size_t)DH * DH;
    wkb[1] = p; p += (size_t)DH * DH;
    wvb[0] = p; p += (size_t)DH * DH;
    wvb[1] = p; p += (size_t)DH * DH;
    bf16* Qb = p; p += (size_t)N * DH;
    bf16* Kb = p; p += (size_t)N * DH;
    bf16* Vt = p; p += (size_t)DH * N;
    bf16* Sb = p; p += (size_t)N * N;

    cast_f32_bf16<<<2048, 256, 0, stream>>>(x, xb, N * D / 4);
    cast_f32_bf16<<<512, 256, 0, stream>>>(Wq[0], wqb[0], DH * DH / 4);
    cast_f32_bf16<<<512, 256, 0, stream>>>(Wq[1], wqb[1], DH * DH / 4);
    cast_f32_bf16<<<512, 256, 0, stream>>>(Wk[0], wkb[0], DH * DH / 4);
    cast_f32_bf16<<<512, 256, 0, stream>>>(Wk[1], wkb[1], DH * DH / 4);
    cast_f32_bf16<<<512, 256, 0, stream>>>(Wv[0], wvb[0], DH * DH / 4);
    cast_f32_bf16<<<512, 256, 0, stream>>>(Wv[1], wvb[1], DH * DH / 4);

    for (int h = 0; h < 2; ++h) {
        const bf16* xh = xb + h * DH;   // 4096 x 1024, row stride D
        // Q = X_h @ Wq^T  (4096 x 1024)
        gemm_bt<bf16><<<dim3(DH / BN, N / BM), 256, 0, stream>>>(
            xh, wqb[h], Qb, DH, D, DH, DH);
        // K = X_h @ Wk^T
        gemm_bt<bf16><<<dim3(DH / BN, N / BM), 256, 0, stream>>>(
            xh, wkb[h], Kb, DH, D, DH, DH);
        // Vt = Wv @ X_h^T  (1024 x 4096): Vt[d,n] = sum_c Wv[d,c] X_h[n,c]
        gemm_bt<bf16><<<dim3(N / BN, DH / BM), 256, 0, stream>>>(
            wvb[h], xh, Vt, DH, DH, D, N);
        // S = Q @ K^T  (4096 x 4096)
        gemm_bt<bf16><<<dim3(N / BN, N / BM), 256, 0, stream>>>(
            Qb, Kb, Sb, DH, DH, DH, N);
        // O = S @ Vt^T -> out[:, h*DH .. ]  : O[n,d] = sum_m S[n,m] Vt[d,m]
        gemm_bt<float><<<dim3(DH / BN, N / BM), 256, 0, stream>>>(
            Sb, Vt, out + h * DH, N, N, N, D);
    }
}

// Round 4
// 154.718 us; speedup vs baseline: 2.5533x; 2.5533x over previous
//
#include <hip/hip_runtime.h>
#include <hip/hip_bf16.h>

// No softmax in the reference => O = (Q K^T) V == Q (K^T V). Reassociation:
//   per head: Q = X_h Wq^T            (4096x1024, K=1024)
//             Kt = Wk X_h^T           (1024x4096, K=1024)
//             Vt = Wv X_h^T           (1024x4096, K=1024)
//             Tt = gemm_bt(Vt, Kt)    (1024x1024, K=4096)  == (K^T V)^T, split-K x4
//             O  = gemm_bt(Q, Tt)     (4096x1024, K=1024)  -> out[:, h*1024:]
// Total 86 GF (vs 189 GF unreassociated). All GEMMs z-batched via pointer
// arrays for >=2 blocks/CU occupancy. m97 structure: 128x128 tile, BK=32,
// 4 waves, global_load_lds width=16, mfma_f32_16x16x32_bf16.

using bf16 = __hip_bfloat16;
typedef __attribute__((ext_vector_type(8))) __bf16 bf16x8;
typedef __attribute__((ext_vector_type(8))) unsigned short u16x8;
typedef __attribute__((ext_vector_type(4))) float f32x4;

#define BM 128
#define BN 128
#define BK 32

struct GB {           // per-z pointer batch (indexed by blockIdx.z, uniform)
    const bf16* A[8];
    const bf16* B[8];
    void* C[8];
};

__device__ __forceinline__ void gload_lds16(const void* g, void* l) {
    __builtin_amdgcn_global_load_lds(
        (const __attribute__((address_space(1))) void*)g,
        (__attribute__((address_space(3))) void*)l, 16, 0, 0);
}

__device__ __forceinline__ void storeC(bf16* C, size_t idx, float v) {
    C[idx] = __float2bfloat16(v);
}
__device__ __forceinline__ void storeC(float* C, size_t idx, float v) {
    C[idx] = v;
}

// A: M x K row-major (stride lda), B: Nd x K row-major (stride ldb)  [B^T form]
// C: M x Nd (stride ldc). grid.x = Nd/128, grid.y = M/128, grid.z = batch.
template<typename OUT_T>
__global__ __launch_bounds__(256, 2)
void gemm_bt_pa(GB g, int K, int lda, int ldb, int ldc)
{
    const bf16* __restrict__ A = g.A[blockIdx.z];
    const bf16* __restrict__ B = g.B[blockIdx.z];
    OUT_T* __restrict__ C = (OUT_T*)g.C[blockIdx.z];

    __shared__ unsigned short As[BM * BK];   // linear (global_load_lds needs it)
    __shared__ unsigned short Bs[BN * BK];

    const int tid  = threadIdx.x;
    const int lane = tid & 63;
    const int wave = tid >> 6;
    const int wm   = wave >> 1;
    const int wn   = wave & 1;

    const int m0 = blockIdx.y * BM;
    const int n0 = blockIdx.x * BN;

    const int fr = lane & 15;
    const int kg = lane >> 4;

    const int srow = tid >> 2;
    const int scol = (tid & 3) * 8;

    f32x4 acc[4][4];
    #pragma unroll
    for (int i = 0; i < 4; ++i)
        #pragma unroll
        for (int j = 0; j < 4; ++j)
            acc[i][j] = {0.f, 0.f, 0.f, 0.f};

    for (int kt = 0; kt < K; kt += BK) {
        #pragma unroll
        for (int r = 0; r < 2; ++r) {
            const bf16* gA = A + (size_t)(m0 + r * 64 + srow) * lda + (kt + scol);
            gload_lds16(gA, &As[(r * 64 + srow) * BK + scol]);
            const bf16* gB = B + (size_t)(n0 + r * 64 + srow) * ldb + (kt + scol);
            gload_lds16(gB, &Bs[(r * 64 + srow) * BK + scol]);
        }
        __syncthreads();

        bf16x8 afrag[4], bfrag[4];
        #pragma unroll
        for (int mi = 0; mi < 4; ++mi)
            afrag[mi] = *(const bf16x8*)&As[(wm * 64 + mi * 16 + fr) * BK + kg * 8];
        #pragma unroll
        for (int ni = 0; ni < 4; ++ni)
            bfrag[ni] = *(const bf16x8*)&Bs[(wn * 64 + ni * 16 + fr) * BK + kg * 8];

        #pragma unroll
        for (int mi = 0; mi < 4; ++mi)
            #pragma unroll
            for (int ni = 0; ni < 4; ++ni)
                acc[mi][ni] = __builtin_amdgcn_mfma_f32_16x16x32_bf16(
                    afrag[mi], bfrag[ni], acc[mi][ni], 0, 0, 0);
        __syncthreads();
    }

    // C/D layout: col = lane&15, row = (lane>>4)*4 + j  [m89-verified]
    #pragma unroll
    for (int mi = 0; mi < 4; ++mi) {
        #pragma unroll
        for (int ni = 0; ni < 4; ++ni) {
            const int col = n0 + wn * 64 + ni * 16 + fr;
            #pragma unroll
            for (int j = 0; j < 4; ++j) {
                const int row = m0 + wm * 64 + mi * 16 + kg * 4 + j;
                storeC(C, (size_t)row * ldc + col, acc[mi][ni][j]);
            }
        }
    }
}

__global__ void cast_f32_bf16(const float* __restrict__ src, bf16* __restrict__ dst, int n4)
{
    int i = blockIdx.x * blockDim.x + threadIdx.x;
    const int stride = gridDim.x * blockDim.x;
    for (; i < n4; i += stride) {
        float4 v = reinterpret_cast<const float4*>(src)[i];
        ushort4 o;
        bf16 h;
        h = __float2bfloat16(v.x); o.x = *reinterpret_cast<unsigned short*>(&h);
        h = __float2bfloat16(v.y); o.y = *reinterpret_cast<unsigned short*>(&h);
        h = __float2bfloat16(v.z); o.z = *reinterpret_cast<unsigned short*>(&h);
        h = __float2bfloat16(v.w); o.w = *reinterpret_cast<unsigned short*>(&h);
        reinterpret_cast<ushort4*>(dst)[i] = o;
    }
}

struct C6 { const float* s[6]; bf16* d[6]; };

__global__ void cast6_f32_bf16(C6 c, int n4)   // grid.y = weight index
{
    const float* __restrict__ src = c.s[blockIdx.y];
    bf16* __restrict__ dst = c.d[blockIdx.y];
    int i = blockIdx.x * blockDim.x + threadIdx.x;
    if (i < n4) {
        float4 v = reinterpret_cast<const float4*>(src)[i];
        ushort4 o;
        bf16 h;
        h = __float2bfloat16(v.x); o.x = *reinterpret_cast<unsigned short*>(&h);
        h = __float2bfloat16(v.y); o.y = *reinterpret_cast<unsigned short*>(&h);
        h = __float2bfloat16(v.z); o.z = *reinterpret_cast<unsigned short*>(&h);
        h = __float2bfloat16(v.w); o.w = *reinterpret_cast<unsigned short*>(&h);
        reinterpret_cast<ushort4*>(dst)[i] = o;
    }
}

// Tt[b][i] = sum_{s=0..3} Tp[(b*4+s)*1M + i], bf16 in, f32 accum, bf16 out
__global__ void reduce_T(const bf16* __restrict__ Tp, bf16* __restrict__ Tt)
{
    const int M1 = 1024 * 1024;
    int t = blockIdx.x * blockDim.x + threadIdx.x;   // 0 .. 256K-1
    int o = t * 8;
    int b = o >> 20;
    int r = o & (M1 - 1);
    const unsigned short* base = (const unsigned short*)Tp + (size_t)b * 4 * M1 + r;
    float acc[8] = {0, 0, 0, 0, 0, 0, 0, 0};
    #pragma unroll
    for (int s = 0; s < 4; ++s) {
        u16x8 v = *(const u16x8*)(base + (size_t)s * M1);
        #pragma unroll
        for (int j = 0; j < 8; ++j)
            acc[j] += __uint_as_float(((unsigned)v[j]) << 16);
    }
    ushort4 o0, o1;
    bf16 h;
    h = __float2bfloat16(acc[0]); o0.x = *(unsigned short*)&h;
    h = __float2bfloat16(acc[1]); o0.y = *(unsigned short*)&h;
    h = __float2bfloat16(acc[2]); o0.z = *(unsigned short*)&h;
    h = __float2bfloat16(acc[3]); o0.w = *(unsigned short*)&h;
    h = __float2bfloat16(acc[4]); o1.x = *(unsigned short*)&h;
    h = __float2bfloat16(acc[5]); o1.y = *(unsigned short*)&h;
    h = __float2bfloat16(acc[6]); o1.z = *(unsigned short*)&h;
    h = __float2bfloat16(acc[7]); o1.w = *(unsigned short*)&h;
    ushort4* dst = (ushort4*)((unsigned short*)Tt + (size_t)b * M1 + r);
    dst[0] = o0;
    dst[1] = o1;
}

extern "C" void kernel_launch(void* const* d_in, const int* in_sizes, int n_in,
                              void* d_out, int out_size, void* d_ws, size_t ws_size,
                              hipStream_t stream)
{
    const int N = 4096, D = 2048, DH = 1024;
    const int M1 = DH * DH;          // 1M elems
    const int M4 = DH * N;           // 4M elems (one head's Kt/Vt/Q)

    const float* x = (const float*)d_in[0];
    float* out = (float*)d_out;

    // workspace layout (<= 76 MB, within the 84 MB proven last round)
    char* w = (char*)d_ws;
    bf16* xb = (bf16*)w;                         // 16 MB; later reused as Tp
    bf16* w6 = (bf16*)(w + (16u << 20));         // 12 MB: wq0,wq1,wk0,wk1,wv0,wv1; later Tt
    bf16* Qb = (bf16*)(w + (28u << 20));         // 16 MB (both heads)
    bf16* Kt = (bf16*)(w + (44u << 20));         // 16 MB (both heads)
    bf16* Vt = (bf16*)(w + (60u << 20));         // 16 MB (both heads)
    bf16* Tp = xb;                               // 8 x 1M bf16 = 16 MB (over dead xb)
    bf16* Tt = w6;                               // 4 MB (over dead wq0,wq1)

    // ---- casts ----
    cast_f32_bf16<<<2048, 256, 0, stream>>>(x, xb, N * D / 4);
    C6 c6;
    for (int i = 0; i < 6; ++i) {
        c6.s[i] = (const float*)d_in[1 + i];
        c6.d[i] = w6 + (size_t)i * M1;
    }
    cast6_f32_bf16<<<dim3(M1 / 4 / 256, 6), 256, 0, stream>>>(c6, M1 / 4);

    bf16* wq[2] = {w6 + 0 * M1, w6 + 1 * M1};
    bf16* wk[2] = {w6 + 2 * M1, w6 + 3 * M1};
    bf16* wv[2] = {w6 + 4 * M1, w6 + 5 * M1};

    GB g;

    // ---- G1: Kt/Vt = W @ X_h^T, z = {Kt0, Vt0, Kt1, Vt1}, 1024 blocks ----
    g.A[0] = wk[0]; g.B[0] = xb + 0 * DH; g.C[0] = Kt + 0 * M4;
    g.A[1] = wv[0]; g.B[1] = xb + 0 * DH; g.C[1] = Vt + 0 * M4;
    g.A[2] = wk[1]; g.B[2] = xb + 1 * DH; g.C[2] = Kt + 1 * M4;
    g.A[3] = wv[1]; g.B[3] = xb + 1 * DH; g.C[3] = Vt + 1 * M4;
    g.A[4] = g.A[0]; g.B[4] = g.B[0]; g.C[4] = g.C[0];
    g.A[5] = g.A[0]; g.B[5] = g.B[0]; g.C[5] = g.C[0];
    g.A[6] = g.A[0]; g.B[6] = g.B[0]; g.C[6] = g.C[0];
    g.A[7] = g.A[0]; g.B[7] = g.B[0]; g.C[7] = g.C[0];
    gemm_bt_pa<bf16><<<dim3(N / BN, DH / BM, 4), 256, 0, stream>>>(g, DH, DH, D, N);

    // ---- G2: Q = X_h @ Wq^T, z = {h0, h1}, 512 blocks ----
    g.A[0] = xb + 0 * DH; g.B[0] = wq[0]; g.C[0] = Qb + 0 * M4;
    g.A[1] = xb + 1 * DH; g.B[1] = wq[1]; g.C[1] = Qb + 1 * M4;
    gemm_bt_pa<bf16><<<dim3(DH / BN, N / BM, 2), 256, 0, stream>>>(g, DH, D, DH, DH);

    // ---- G3: Tt partials = gemm_bt(Vt_h + s*1024, Kt_h + s*1024), z = h*4+s, 512 blocks ----
    for (int z = 0; z < 8; ++z) {
        int b = z >> 2, s = z & 3;
        g.A[z] = Vt + (size_t)b * M4 + s * 1024;
        g.B[z] = Kt + (size_t)b * M4 + s * 1024;
        g.C[z] = Tp + (size_t)z * M1;
    }
    gemm_bt_pa<bf16><<<dim3(DH / BN, DH / BM, 8), 256, 0, stream>>>(g, 1024, N, N, DH);

    // ---- reduce partials -> Tt (bf16) ----
    reduce_T<<<(2 * M1 / 8) / 256, 256, 0, stream>>>(Tp, Tt);

    // ---- G4: O = gemm_bt(Q_h, Tt_h) -> f32 out[:, h*DH:], 512 blocks ----
    g.A[0] = Qb + 0 * M4; g.B[0] = Tt + 0 * M1; g.C[0] = out + 0 * DH;
    g.A[1] = Qb + 1 * M4; g.B[1] = Tt + 1 * M1; g.C[1] = out + 1 * DH;
    gemm_bt_pa<float><<<dim3(DH / BN, N / BM, 2), 256, 0, stream>>>(g, DH, DH, DH, D);
}

// Round 5
// 135.523 us; speedup vs baseline: 2.9149x; 1.1416x over previous
//
#include <hip/hip_runtime.h>
#include <hip/hip_bf16.h>

// Gram reassociation (no softmax in reference):
//   O_h = Q K^T V = X_h * U_h,  U_h = Wq^T Wk G Wv^T,  G = X_h^T X_h
// FLOPs: 47 GF (vs 86 reassoc-once, 189 naive).
// bt-form chain (contract last dims, gemm_bt(A,B) = A B^T):
//   M  = gemm_bt(WqT, WkT)           (= Wq^T Wk)
//   G  = gemm_bt(Xt_h, Xt_h)         (= X_h^T X_h, symmetric)
//   Yt = gemm_bt(M, G)               (= M G)
//   Ut = gemm_bt(Wv, Yt)             (= Wv G M^T = U^T)
//   O  = gemm_bt(X_h, Ut_h) -> f32   (= X U)
// All small GEMMs split-K with bf16 partials staged in d_out (dead until O).
// Latency model: time ~ rounds_of_512_blocks x k_iters x ~1800cy; so split-K
// everywhere to cut iters, and batch z to fill CUs.

using bf16 = __hip_bfloat16;
typedef __attribute__((ext_vector_type(8))) __bf16 bf16x8;
typedef __attribute__((ext_vector_type(8))) unsigned short u16x8;
typedef __attribute__((ext_vector_type(4))) float f32x4;

#define M1 (1024 * 1024)

struct GB {   // per-z batch (blockIdx.z-indexed, wave-uniform)
    const bf16* A[20];
    const bf16* B[20];
    void*       C[20];
    int lda[20];
    int ldb[20];
};

__device__ __forceinline__ void gload_lds16(const void* g, void* l) {
    __builtin_amdgcn_global_load_lds(
        (const __attribute__((address_space(1))) void*)g,
        (__attribute__((address_space(3))) void*)l, 16, 0, 0);
}

__device__ __forceinline__ void storeC(bf16* C, size_t idx, float v) {
    C[idx] = __float2bfloat16(v);
}
__device__ __forceinline__ void storeC(float* C, size_t idx, float v) {
    C[idx] = v;
}

// A: M x K row-major (lda), B: Nd x K row-major (ldb); C = A B^T (ldc).
// grid: (Nd/BN_, Mrows/BM_, z). 4 waves in 2x2 over (BM_/2)x(BN_/2) subtiles.
template<int BM_, int BN_, typename OUT_T>
__global__ __launch_bounds__(256, 2)
void gemm_bt_pa(GB g, int Ksub, int ldc)
{
    const bf16* __restrict__ A = g.A[blockIdx.z];
    const bf16* __restrict__ B = g.B[blockIdx.z];
    OUT_T* __restrict__ C = (OUT_T*)g.C[blockIdx.z];
    const int lda = g.lda[blockIdx.z];
    const int ldb = g.ldb[blockIdx.z];

    __shared__ unsigned short As[BM_ * 32];   // linear (global_load_lds)
    __shared__ unsigned short Bs[BN_ * 32];

    constexpr int MI = BM_ / 32;   // 16-row fragments per wave (rows)
    constexpr int NI = BN_ / 32;   // 16-col fragments per wave (cols)

    const int tid  = threadIdx.x;
    const int lane = tid & 63;
    const int wave = tid >> 6;
    const int wm   = wave >> 1;    // row half
    const int wn   = wave & 1;     // col half

    const int m0 = blockIdx.y * BM_;
    const int n0 = blockIdx.x * BN_;

    const int fr = lane & 15;
    const int kg = lane >> 4;

    const int srow = tid >> 2;          // 0..63
    const int scol = (tid & 3) * 8;     // 0,8,16,24

    f32x4 acc[MI][NI];
    #pragma unroll
    for (int i = 0; i < MI; ++i)
        #pragma unroll
        for (int j = 0; j < NI; ++j)
            acc[i][j] = {0.f, 0.f, 0.f, 0.f};

    for (int kt = 0; kt < Ksub; kt += 32) {
        #pragma unroll
        for (int r = 0; r < BM_ / 64; ++r) {
            const bf16* gA = A + (size_t)(m0 + r * 64 + srow) * lda + (kt + scol);
            gload_lds16(gA, &As[(r * 64 + srow) * 32 + scol]);
        }
        #pragma unroll
        for (int r = 0; r < BN_ / 64; ++r) {
            const bf16* gB = B + (size_t)(n0 + r * 64 + srow) * ldb + (kt + scol);
            gload_lds16(gB, &Bs[(r * 64 + srow) * 32 + scol]);
        }
        __syncthreads();

        bf16x8 afrag[MI], bfrag[NI];
        #pragma unroll
        for (int mi = 0; mi < MI; ++mi)
            afrag[mi] = *(const bf16x8*)&As[(wm * (BM_ / 2) + mi * 16 + fr) * 32 + kg * 8];
        #pragma unroll
        for (int ni = 0; ni < NI; ++ni)
            bfrag[ni] = *(const bf16x8*)&Bs[(wn * (BN_ / 2) + ni * 16 + fr) * 32 + kg * 8];

        #pragma unroll
        for (int mi = 0; mi < MI; ++mi)
            #pragma unroll
            for (int ni = 0; ni < NI; ++ni)
                acc[mi][ni] = __builtin_amdgcn_mfma_f32_16x16x32_bf16(
                    afrag[mi], bfrag[ni], acc[mi][ni], 0, 0, 0);
        __syncthreads();
    }

    // C/D layout: col = lane&15, row = (lane>>4)*4 + j  [m89-verified]
    #pragma unroll
    for (int mi = 0; mi < MI; ++mi) {
        #pragma unroll
        for (int ni = 0; ni < NI; ++ni) {
            const int col = n0 + wn * (BN_ / 2) + ni * 16 + fr;
            #pragma unroll
            for (int j = 0; j < 4; ++j) {
                const int row = m0 + wm * (BM_ / 2) + mi * 16 + kg * 4 + j;
                storeC(C, (size_t)row * ldc + col, acc[mi][ni][j]);
            }
        }
    }
}

// ---------------- prep: casts + transposes ----------------

__device__ __forceinline__ ushort4 cvt4(float4 v) {
    ushort4 o; bf16 h;
    h = __float2bfloat16(v.x); o.x = *(unsigned short*)&h;
    h = __float2bfloat16(v.y); o.y = *(unsigned short*)&h;
    h = __float2bfloat16(v.z); o.z = *(unsigned short*)&h;
    h = __float2bfloat16(v.w); o.w = *(unsigned short*)&h;
    return o;
}

struct PrepArgs {
    const float* x;
    const float* w[4];    // Wq1, Wq2, Wk1, Wk2 (to transpose)
    const float* wv[2];   // Wv1, Wv2 (straight)
    bf16* xb;             // 4096x2048 bf16
    bf16* xt;             // 2048x4096 bf16 (= x^T)
    bf16* wdst;           // WqT0,WqT1,WkT0,WkT1,Wv0,Wv1 (6 x 1M)
};

// 64x64 f32 tile -> bf16 transpose (+ optional straight copy)
__device__ void xpose64(const float* __restrict__ src, int ldsrc,
                        int r0, int c0,
                        bf16* __restrict__ dstS, int ldS,
                        bf16* __restrict__ dstT, int ldT,
                        float (*tile)[65], int t)
{
    const int tr  = t >> 4;         // 0..15
    const int tc4 = (t & 15) * 4;   // 0,4,..,60
    #pragma unroll
    for (int ph = 0; ph < 4; ++ph) {
        const int row = ph * 16 + tr;
        float4 v = *(const float4*)(src + (size_t)(r0 + row) * ldsrc + c0 + tc4);
        tile[row][tc4 + 0] = v.x;
        tile[row][tc4 + 1] = v.y;
        tile[row][tc4 + 2] = v.z;
        tile[row][tc4 + 3] = v.w;
        if (dstS)
            *(ushort4*)((unsigned short*)dstS + (size_t)(r0 + row) * ldS + c0 + tc4) = cvt4(v);
    }
    __syncthreads();
    #pragma unroll
    for (int ph = 0; ph < 4; ++ph) {
        const int crow = ph * 16 + tr;
        float4 v = {tile[tc4 + 0][crow], tile[tc4 + 1][crow],
                    tile[tc4 + 2][crow], tile[tc4 + 3][crow]};
        *(ushort4*)((unsigned short*)dstT + (size_t)(c0 + crow) * ldT + r0 + tc4) = cvt4(v);
    }
}

__global__ void prep(PrepArgs p)
{
    __shared__ float tile[64][65];
    const int b = blockIdx.x;
    const int t = threadIdx.x;

    if (b < 2048) {                       // x: cast + transpose
        const int n0 = (b & 63) * 64;
        const int c0 = (b >> 6) * 64;
        xpose64(p.x, 2048, n0, c0, p.xb, 2048, p.xt, 4096, tile, t);
    } else if (b < 3072) {                // Wq/Wk transpose-cast
        const int i = b - 2048;
        const int mat = i >> 8;           // 0..3
        const int tl  = i & 255;
        const int r0 = (tl & 15) * 64;
        const int c0 = (tl >> 4) * 64;
        xpose64(p.w[mat], 1024, r0, c0, nullptr, 0,
                p.wdst + (size_t)mat * M1, 1024, tile, t);
    } else {                              // Wv straight cast
        const int i = b - 3072;
        const int mat = i >> 9;           // 0..1
        const int blk = i & 511;
        const size_t off = (size_t)blk * 2048 + t * 8;
        float4 v0 = *(const float4*)(p.wv[mat] + off);
        float4 v1 = *(const float4*)(p.wv[mat] + off + 4);
        unsigned short* d = (unsigned short*)p.wdst + (size_t)(4 + mat) * M1 + off;
        *(ushort4*)d       = cvt4(v0);
        *(ushort4*)(d + 4) = cvt4(v1);
    }
}

// ---------------- split-K reduces (bf16 partials, f32 accum) ----------------

__device__ __forceinline__ void reduce_slices(const unsigned short* src,
                                              unsigned short* dst,
                                              int h, int r, int nslice)
{
    float acc[8] = {0, 0, 0, 0, 0, 0, 0, 0};
    for (int s = 0; s < nslice; ++s) {
        u16x8 v = *(const u16x8*)(src + ((size_t)(h * nslice + s) << 20) + r);
        #pragma unroll
        for (int j = 0; j < 8; ++j)
            acc[j] += __uint_as_float(((unsigned)v[j]) << 16);
    }
    u16x8 o;
    #pragma unroll
    for (int j = 0; j < 8; ++j) {
        bf16 hh = __float2bfloat16(acc[j]);
        o[j] = *(unsigned short*)&hh;
    }
    *(u16x8*)(dst + ((size_t)h << 20) + r) = o;
}

// blocks 0..1023: G (8 slices, from d_out scratch); 1024..2047: M (2 slices)
__global__ void reduce_GM(const unsigned short* Gp, const unsigned short* Mp,
                          unsigned short* Gd, unsigned short* Md)
{
    const int b = blockIdx.x, t = threadIdx.x;
    if (b < 1024) {
        const int e = (b * 256 + t) * 8;
        reduce_slices(Gp, Gd, e >> 20, e & (M1 - 1), 8);
    } else {
        const int e = ((b - 1024) * 256 + t) * 8;
        reduce_slices(Mp, Md, e >> 20, e & (M1 - 1), 2);
    }
}

__global__ void reduce_4(const unsigned short* Sp, unsigned short* Dd)
{
    const int e = (blockIdx.x * 256 + threadIdx.x) * 8;
    reduce_slices(Sp, Dd, e >> 20, e & (M1 - 1), 4);
}

// ---------------- driver ----------------

extern "C" void kernel_launch(void* const* d_in, const int* in_sizes, int n_in,
                              void* d_out, int out_size, void* d_ws, size_t ws_size,
                              hipStream_t stream)
{
    // ws layout (bf16 elems; 1M = 1<<20): peak 68 MB
    bf16* xb   = (bf16*)d_ws;                  // 8M elems
    bf16* xt   = xb + 8 * M1;                  // 8M
    bf16* wdst = xt + 8 * M1;                  // 6M: WqT0,WqT1,WkT0,WkT1,Wv0,Wv1
    bf16* Mp   = wdst + 6 * M1;                // 4M (M split-K partials)
    bf16* Mb   = Mp + 4 * M1;                  // 2M
    bf16* Gb   = Mb + 2 * M1;                  // 2M
    bf16* Ytb  = Gb + 2 * M1;                  // 2M
    bf16* Utb  = Ytb + 2 * M1;                 // 2M  (end: 34M elems = 68 MB)

    bf16* scr = (bf16*)d_out;                  // 32 MB scratch until final O

    // L1: prep (x cast+transpose, WqT/WkT transpose-cast, Wv cast)
    PrepArgs pa;
    pa.x = (const float*)d_in[0];
    pa.w[0] = (const float*)d_in[1];  pa.w[1] = (const float*)d_in[2];   // Wq1, Wq2
    pa.w[2] = (const float*)d_in[3];  pa.w[3] = (const float*)d_in[4];   // Wk1, Wk2
    pa.wv[0] = (const float*)d_in[5]; pa.wv[1] = (const float*)d_in[6];  // Wv1, Wv2
    pa.xb = xb; pa.xt = xt; pa.wdst = wdst;
    prep<<<4096, 256, 0, stream>>>(pa);

    GB g;

    // L2: batch1 — z 0..15: G_h split-K8 (Ksub=512); z 16..19: M_h split-K2 (Ksub=512)
    for (int z = 0; z < 16; ++z) {
        const int h = z >> 3, s = z & 7;
        g.A[z] = xt + (size_t)h * 4 * M1 + s * 512;  g.lda[z] = 4096;
        g.B[z] = g.A[z];                             g.ldb[z] = 4096;
        g.C[z] = (bf16*)scr + (size_t)z * M1;        // Gp in d_out
    }
    for (int z = 16; z < 20; ++z) {
        const int j = z - 16, h = j >> 1, s = j & 1;
        g.A[z] = wdst + (size_t)h * M1 + s * 512;           g.lda[z] = 1024;  // WqT_h
        g.B[z] = wdst + (size_t)(2 + h) * M1 + s * 512;     g.ldb[z] = 1024;  // WkT_h
        g.C[z] = Mp + (size_t)j * M1;
    }
    gemm_bt_pa<128, 128, bf16><<<dim3(8, 8, 20), 256, 0, stream>>>(g, 512, 1024);

    // L3: reduce G (8 slices, d_out) and M (2 slices, ws)
    reduce_GM<<<2048, 256, 0, stream>>>((const unsigned short*)scr, (const unsigned short*)Mp,
                                        (unsigned short*)Gb, (unsigned short*)Mb);

    // L4: Yt = gemm_bt(M, G) = M G  (split-K4, Ksub=256), partials in d_out
    for (int z = 0; z < 8; ++z) {
        const int h = z >> 2, s = z & 3;
        g.A[z] = Mb + (size_t)h * M1 + s * 256;  g.lda[z] = 1024;
        g.B[z] = Gb + (size_t)h * M1 + s * 256;  g.ldb[z] = 1024;
        g.C[z] = (bf16*)scr + (size_t)z * M1;
    }
    gemm_bt_pa<128, 128, bf16><<<dim3(8, 8, 8), 256, 0, stream>>>(g, 256, 1024);

    // L5: reduce Yt
    reduce_4<<<1024, 256, 0, stream>>>((const unsigned short*)scr, (unsigned short*)Ytb);

    // L6: Ut = gemm_bt(Wv, Yt) = Wv G M^T = U^T  (split-K4), partials in d_out
    for (int z = 0; z < 8; ++z) {
        const int h = z >> 2, s = z & 3;
        g.A[z] = wdst + (size_t)(4 + h) * M1 + s * 256;  g.lda[z] = 1024;  // Wv_h
        g.B[z] = Ytb + (size_t)h * M1 + s * 256;         g.ldb[z] = 1024;
        g.C[z] = (bf16*)scr + (size_t)z * M1;
    }
    gemm_bt_pa<128, 128, bf16><<<dim3(8, 8, 8), 256, 0, stream>>>(g, 256, 1024);

    // L7: reduce Ut
    reduce_4<<<1024, 256, 0, stream>>>((const unsigned short*)scr, (unsigned short*)Utb);

    // L8: O_h = gemm_bt(X_h, Ut_h) -> f32 out[:, h*1024:]  (128x64 tile, 1024 blocks)
    for (int z = 0; z < 2; ++z) {
        g.A[z] = xb + (size_t)z * 1024;   g.lda[z] = 2048;
        g.B[z] = Utb + (size_t)z * M1;    g.ldb[z] = 1024;
        g.C[z] = (float*)d_out + (size_t)z * 1024;
    }
    gemm_bt_pa<128, 64, float><<<dim3(16, 32, 2), 256, 0, stream>>>(g, 1024, 2048);
}

// Round 6
// 126.723 us; speedup vs baseline: 3.1173x; 1.0694x over previous
//
#include <hip/hip_runtime.h>
#include <hip/hip_bf16.h>

// Gram reassociation (no softmax in reference):
//   O_h = Q K^T V = X_h * U_h,  U_h = Wq^T Wk G Wv^T,  G = X_h^T X_h
// Chain (bt-form, gemm_bt(A,B) = A B^T, contract last dims):
//   M  = gemm_bt(WqT, WkT); G = gemm_bt(Xt_h, Xt_h)   [one batched launch]
//   Yt = gemm_bt(M, G); Ut = gemm_bt(Wv, Yt); O = gemm_bt(X_h, Ut) -> f32
// Split-K partials (bf16) staged in d_out while it's dead; reduced between.
// R5 additions: XCD-chunked block swizzle (T1) on all GEMMs — kills the 4.3x
// cross-XCD over-fetch seen in rocprof (L2: 86 MB fetched vs 20 MB unique);
// __launch_bounds__(256,4) for 4 blocks/CU (was ~2.5) to halve latency rounds.

using bf16 = __hip_bfloat16;
typedef __attribute__((ext_vector_type(8))) __bf16 bf16x8;
typedef __attribute__((ext_vector_type(8))) unsigned short u16x8;
typedef __attribute__((ext_vector_type(4))) float f32x4;

#define M1 (1024 * 1024)

struct GB {   // per-z batch (bz-indexed, wave-uniform)
    const bf16* A[20];
    const bf16* B[20];
    void*       C[20];
    int lda[20];
    int ldb[20];
};

__device__ __forceinline__ void gload_lds16(const void* g, void* l) {
    __builtin_amdgcn_global_load_lds(
        (const __attribute__((address_space(1))) void*)g,
        (__attribute__((address_space(3))) void*)l, 16, 0, 0);
}

__device__ __forceinline__ void storeC(bf16* C, size_t idx, float v) {
    C[idx] = __float2bfloat16(v);
}
__device__ __forceinline__ void storeC(float* C, size_t idx, float v) {
    C[idx] = v;
}

// A: M x K row-major (lda), B: Nd x K row-major (ldb); C = A B^T (ldc).
// grid: (Nd/BN_, Mrows/BM_, z). 4 waves in 2x2 over (BM_/2)x(BN_/2) subtiles.
// XCD-chunked swizzle: requires gridDim.x*y*z % 8 == 0 (all our launches).
template<int BM_, int BN_, typename OUT_T>
__global__ __launch_bounds__(256, 4)
void gemm_bt_pa(GB g, int Ksub, int ldc)
{
    // ---- T1: chunked XCD swizzle of the linearized block id ----
    const int gx = gridDim.x, gy = gridDim.y;
    const int nwg = gx * gy * gridDim.z;
    const int orig = blockIdx.x + gx * (blockIdx.y + gy * blockIdx.z);
    const int cpx = nwg >> 3;                       // nwg % 8 == 0
    const int wg = (orig & 7) * cpx + (orig >> 3);  // contiguous chunk per XCD
    const int bx = wg % gx;
    const int by = (wg / gx) % gy;
    const int bz = wg / (gx * gy);

    const bf16* __restrict__ A = g.A[bz];
    const bf16* __restrict__ B = g.B[bz];
    OUT_T* __restrict__ C = (OUT_T*)g.C[bz];
    const int lda = g.lda[bz];
    const int ldb = g.ldb[bz];

    __shared__ unsigned short As[BM_ * 32];   // linear (global_load_lds)
    __shared__ unsigned short Bs[BN_ * 32];

    constexpr int MI = BM_ / 32;
    constexpr int NI = BN_ / 32;

    const int tid  = threadIdx.x;
    const int lane = tid & 63;
    const int wave = tid >> 6;
    const int wm   = wave >> 1;
    const int wn   = wave & 1;

    const int m0 = by * BM_;
    const int n0 = bx * BN_;

    const int fr = lane & 15;
    const int kg = lane >> 4;

    const int srow = tid >> 2;
    const int scol = (tid & 3) * 8;

    f32x4 acc[MI][NI];
    #pragma unroll
    for (int i = 0; i < MI; ++i)
        #pragma unroll
        for (int j = 0; j < NI; ++j)
            acc[i][j] = {0.f, 0.f, 0.f, 0.f};

    for (int kt = 0; kt < Ksub; kt += 32) {
        #pragma unroll
        for (int r = 0; r < BM_ / 64; ++r) {
            const bf16* gA = A + (size_t)(m0 + r * 64 + srow) * lda + (kt + scol);
            gload_lds16(gA, &As[(r * 64 + srow) * 32 + scol]);
        }
        #pragma unroll
        for (int r = 0; r < BN_ / 64; ++r) {
            const bf16* gB = B + (size_t)(n0 + r * 64 + srow) * ldb + (kt + scol);
            gload_lds16(gB, &Bs[(r * 64 + srow) * 32 + scol]);
        }
        __syncthreads();

        bf16x8 afrag[MI], bfrag[NI];
        #pragma unroll
        for (int mi = 0; mi < MI; ++mi)
            afrag[mi] = *(const bf16x8*)&As[(wm * (BM_ / 2) + mi * 16 + fr) * 32 + kg * 8];
        #pragma unroll
        for (int ni = 0; ni < NI; ++ni)
            bfrag[ni] = *(const bf16x8*)&Bs[(wn * (BN_ / 2) + ni * 16 + fr) * 32 + kg * 8];

        #pragma unroll
        for (int mi = 0; mi < MI; ++mi)
            #pragma unroll
            for (int ni = 0; ni < NI; ++ni)
                acc[mi][ni] = __builtin_amdgcn_mfma_f32_16x16x32_bf16(
                    afrag[mi], bfrag[ni], acc[mi][ni], 0, 0, 0);
        __syncthreads();
    }

    // C/D layout: col = lane&15, row = (lane>>4)*4 + j  [m89-verified]
    #pragma unroll
    for (int mi = 0; mi < MI; ++mi) {
        #pragma unroll
        for (int ni = 0; ni < NI; ++ni) {
            const int col = n0 + wn * (BN_ / 2) + ni * 16 + fr;
            #pragma unroll
            for (int j = 0; j < 4; ++j) {
                const int row = m0 + wm * (BM_ / 2) + mi * 16 + kg * 4 + j;
                storeC(C, (size_t)row * ldc + col, acc[mi][ni][j]);
            }
        }
    }
}

// ---------------- prep: casts + transposes ----------------

__device__ __forceinline__ ushort4 cvt4(float4 v) {
    ushort4 o; bf16 h;
    h = __float2bfloat16(v.x); o.x = *(unsigned short*)&h;
    h = __float2bfloat16(v.y); o.y = *(unsigned short*)&h;
    h = __float2bfloat16(v.z); o.z = *(unsigned short*)&h;
    h = __float2bfloat16(v.w); o.w = *(unsigned short*)&h;
    return o;
}

struct PrepArgs {
    const float* x;
    const float* w[4];    // Wq1, Wq2, Wk1, Wk2 (to transpose)
    const float* wv[2];   // Wv1, Wv2 (straight)
    bf16* xb;             // 4096x2048 bf16
    bf16* xt;             // 2048x4096 bf16 (= x^T)
    bf16* wdst;           // WqT0,WqT1,WkT0,WkT1,Wv0,Wv1 (6 x 1M)
};

__device__ void xpose64(const float* __restrict__ src, int ldsrc,
                        int r0, int c0,
                        bf16* __restrict__ dstS, int ldS,
                        bf16* __restrict__ dstT, int ldT,
                        float (*tile)[65], int t)
{
    const int tr  = t >> 4;
    const int tc4 = (t & 15) * 4;
    #pragma unroll
    for (int ph = 0; ph < 4; ++ph) {
        const int row = ph * 16 + tr;
        float4 v = *(const float4*)(src + (size_t)(r0 + row) * ldsrc + c0 + tc4);
        tile[row][tc4 + 0] = v.x;
        tile[row][tc4 + 1] = v.y;
        tile[row][tc4 + 2] = v.z;
        tile[row][tc4 + 3] = v.w;
        if (dstS)
            *(ushort4*)((unsigned short*)dstS + (size_t)(r0 + row) * ldS + c0 + tc4) = cvt4(v);
    }
    __syncthreads();
    #pragma unroll
    for (int ph = 0; ph < 4; ++ph) {
        const int crow = ph * 16 + tr;
        float4 v = {tile[tc4 + 0][crow], tile[tc4 + 1][crow],
                    tile[tc4 + 2][crow], tile[tc4 + 3][crow]};
        *(ushort4*)((unsigned short*)dstT + (size_t)(c0 + crow) * ldT + r0 + tc4) = cvt4(v);
    }
}

__global__ void prep(PrepArgs p)
{
    __shared__ float tile[64][65];
    const int b = blockIdx.x;
    const int t = threadIdx.x;

    if (b < 2048) {                       // x: cast + transpose
        const int n0 = (b & 63) * 64;
        const int c0 = (b >> 6) * 64;
        xpose64(p.x, 2048, n0, c0, p.xb, 2048, p.xt, 4096, tile, t);
    } else if (b < 3072) {                // Wq/Wk transpose-cast
        const int i = b - 2048;
        const int mat = i >> 8;
        const int tl  = i & 255;
        const int r0 = (tl & 15) * 64;
        const int c0 = (tl >> 4) * 64;
        xpose64(p.w[mat], 1024, r0, c0, nullptr, 0,
                p.wdst + (size_t)mat * M1, 1024, tile, t);
    } else {                              // Wv straight cast
        const int i = b - 3072;
        const int mat = i >> 9;
        const int blk = i & 511;
        const size_t off = (size_t)blk * 2048 + t * 8;
        float4 v0 = *(const float4*)(p.wv[mat] + off);
        float4 v1 = *(const float4*)(p.wv[mat] + off + 4);
        unsigned short* d = (unsigned short*)p.wdst + (size_t)(4 + mat) * M1 + off;
        *(ushort4*)d       = cvt4(v0);
        *(ushort4*)(d + 4) = cvt4(v1);
    }
}

// ---------------- split-K reduces (bf16 partials, f32 accum) ----------------

__device__ __forceinline__ void reduce_slices(const unsigned short* src,
                                              unsigned short* dst,
                                              int h, int r, int nslice)
{
    float acc[8] = {0, 0, 0, 0, 0, 0, 0, 0};
    for (int s = 0; s < nslice; ++s) {
        u16x8 v = *(const u16x8*)(src + ((size_t)(h * nslice + s) << 20) + r);
        #pragma unroll
        for (int j = 0; j < 8; ++j)
            acc[j] += __uint_as_float(((unsigned)v[j]) << 16);
    }
    u16x8 o;
    #pragma unroll
    for (int j = 0; j < 8; ++j) {
        bf16 hh = __float2bfloat16(acc[j]);
        o[j] = *(unsigned short*)&hh;
    }
    *(u16x8*)(dst + ((size_t)h << 20) + r) = o;
}

__global__ void reduce_GM(const unsigned short* Gp, const unsigned short* Mp,
                          unsigned short* Gd, unsigned short* Md)
{
    const int b = blockIdx.x, t = threadIdx.x;
    if (b < 1024) {
        const int e = (b * 256 + t) * 8;
        reduce_slices(Gp, Gd, e >> 20, e & (M1 - 1), 8);
    } else {
        const int e = ((b - 1024) * 256 + t) * 8;
        reduce_slices(Mp, Md, e >> 20, e & (M1 - 1), 2);
    }
}

__global__ void reduce_4(const unsigned short* Sp, unsigned short* Dd)
{
    const int e = (blockIdx.x * 256 + threadIdx.x) * 8;
    reduce_slices(Sp, Dd, e >> 20, e & (M1 - 1), 4);
}

// ---------------- driver ----------------

extern "C" void kernel_launch(void* const* d_in, const int* in_sizes, int n_in,
                              void* d_out, int out_size, void* d_ws, size_t ws_size,
                              hipStream_t stream)
{
    // ws layout (bf16 elems): peak 68 MB
    bf16* xb   = (bf16*)d_ws;                  // 8M elems
    bf16* xt   = xb + 8 * M1;                  // 8M
    bf16* wdst = xt + 8 * M1;                  // 6M
    bf16* Mp   = wdst + 6 * M1;                // 4M
    bf16* Mb   = Mp + 4 * M1;                  // 2M
    bf16* Gb   = Mb + 2 * M1;                  // 2M
    bf16* Ytb  = Gb + 2 * M1;                  // 2M
    bf16* Utb  = Ytb + 2 * M1;                 // 2M

    bf16* scr = (bf16*)d_out;                  // 32 MB scratch until final O

    PrepArgs pa;
    pa.x = (const float*)d_in[0];
    pa.w[0] = (const float*)d_in[1];  pa.w[1] = (const float*)d_in[2];
    pa.w[2] = (const float*)d_in[3];  pa.w[3] = (const float*)d_in[4];
    pa.wv[0] = (const float*)d_in[5]; pa.wv[1] = (const float*)d_in[6];
    pa.xb = xb; pa.xt = xt; pa.wdst = wdst;
    prep<<<4096, 256, 0, stream>>>(pa);

    GB g;

    // L2: z 0..15: G_h split-K8 (Ksub=512); z 16..19: M_h split-K2. 1280 blocks.
    for (int z = 0; z < 16; ++z) {
        const int h = z >> 3, s = z & 7;
        g.A[z] = xt + (size_t)h * 4 * M1 + s * 512;  g.lda[z] = 4096;
        g.B[z] = g.A[z];                             g.ldb[z] = 4096;
        g.C[z] = (bf16*)scr + (size_t)z * M1;
    }
    for (int z = 16; z < 20; ++z) {
        const int j = z - 16, h = j >> 1, s = j & 1;
        g.A[z] = wdst + (size_t)h * M1 + s * 512;           g.lda[z] = 1024;
        g.B[z] = wdst + (size_t)(2 + h) * M1 + s * 512;     g.ldb[z] = 1024;
        g.C[z] = Mp + (size_t)j * M1;
    }
    gemm_bt_pa<128, 128, bf16><<<dim3(8, 8, 20), 256, 0, stream>>>(g, 512, 1024);

    reduce_GM<<<2048, 256, 0, stream>>>((const unsigned short*)scr, (const unsigned short*)Mp,
                                        (unsigned short*)Gb, (unsigned short*)Mb);

    // L4: Yt = M G (split-K4, Ksub=256), 512 blocks
    for (int z = 0; z < 8; ++z) {
        const int h = z >> 2, s = z & 3;
        g.A[z] = Mb + (size_t)h * M1 + s * 256;  g.lda[z] = 1024;
        g.B[z] = Gb + (size_t)h * M1 + s * 256;  g.ldb[z] = 1024;
        g.C[z] = (bf16*)scr + (size_t)z * M1;
    }
    gemm_bt_pa<128, 128, bf16><<<dim3(8, 8, 8), 256, 0, stream>>>(g, 256, 1024);

    reduce_4<<<1024, 256, 0, stream>>>((const unsigned short*)scr, (unsigned short*)Ytb);

    // L6: Ut = Wv Yt^T... = gemm_bt(Wv, Yt) (split-K4), 512 blocks
    for (int z = 0; z < 8; ++z) {
        const int h = z >> 2, s = z & 3;
        g.A[z] = wdst + (size_t)(4 + h) * M1 + s * 256;  g.lda[z] = 1024;
        g.B[z] = Ytb + (size_t)h * M1 + s * 256;         g.ldb[z] = 1024;
        g.C[z] = (bf16*)scr + (size_t)z * M1;
    }
    gemm_bt_pa<128, 128, bf16><<<dim3(8, 8, 8), 256, 0, stream>>>(g, 256, 1024);

    reduce_4<<<1024, 256, 0, stream>>>((const unsigned short*)scr, (unsigned short*)Utb);

    // L8: O_h = gemm_bt(X_h, Ut_h) -> f32 out[:, h*1024:]  (128x64 tile, 1024 blocks)
    for (int z = 0; z < 2; ++z) {
        g.A[z] = xb + (size_t)z * 1024;   g.lda[z] = 2048;
        g.B[z] = Utb + (size_t)z * M1;    g.ldb[z] = 1024;
        g.C[z] = (float*)d_out + (size_t)z * 1024;
    }
    gemm_bt_pa<128, 64, float><<<dim3(16, 32, 2), 256, 0, stream>>>(g, 1024, 2048);
}